// Round 1
// baseline (277.034 us; speedup 1.0000x reference)
//
#include <hip/hip_runtime.h>

#define NB 2048
#define NT 256

// log(I0(x)) via Abramowitz & Stegun 9.8.1 / 9.8.2 (|rel err| < ~2e-7)
__device__ __forceinline__ float log_i0(float x) {
    x = fabsf(x);
    if (x <= 3.75f) {
        float t2 = x * (1.0f / 3.75f);
        t2 = t2 * t2;
        float p = 0.0045813f;
        p = fmaf(p, t2, 0.0360768f);
        p = fmaf(p, t2, 0.2659732f);
        p = fmaf(p, t2, 1.2067492f);
        p = fmaf(p, t2, 3.0899424f);
        p = fmaf(p, t2, 3.5156229f);
        p = fmaf(p, t2, 1.0f);
        return __logf(p);
    } else {
        float r = 3.75f / x;
        float p = 0.00392377f;
        p = fmaf(p, r, -0.01647633f);
        p = fmaf(p, r, 0.02635537f);
        p = fmaf(p, r, -0.02057706f);
        p = fmaf(p, r, 0.00916281f);
        p = fmaf(p, r, -0.00157565f);
        p = fmaf(p, r, 0.00225319f);
        p = fmaf(p, r, 0.01328592f);
        p = fmaf(p, r, 0.39894228f);
        return x - 0.5f * __logf(x) + __logf(p);
    }
}

__device__ __forceinline__ float elem_term(float e, float o, float inv_var, float half_iv) {
    // term1 - log_bessel  (the reference returns -(sum(log_bessel - term1)))
    return fmaf(half_iv * e, e, -log_i0(e * o * inv_var));
}

__global__ __launch_bounds__(NT) void rician_partial(
    const float4* __restrict__ est4, const float4* __restrict__ obs4,
    const float* __restrict__ est, const float* __restrict__ obs,
    const float* __restrict__ std_noise,
    float* __restrict__ partial, int n4, int n)
{
    const float s = std_noise[0];
    const float inv_var = 1.0f / (s * s);
    const float half_iv = 0.5f * inv_var;

    float acc = 0.0f;
    int idx = blockIdx.x * NT + threadIdx.x;
    const int stride = gridDim.x * NT;
    for (int i = idx; i < n4; i += stride) {
        float4 e = est4[i];
        float4 o = obs4[i];
        acc += elem_term(e.x, o.x, inv_var, half_iv);
        acc += elem_term(e.y, o.y, inv_var, half_iv);
        acc += elem_term(e.z, o.z, inv_var, half_iv);
        acc += elem_term(e.w, o.w, inv_var, half_iv);
    }
    // scalar tail (n not multiple of 4) handled by first thread only
    if (blockIdx.x == 0 && threadIdx.x == 0) {
        for (int i = n4 * 4; i < n; ++i)
            acc += elem_term(est[i], obs[i], inv_var, half_iv);
    }

    // wave-64 reduce
    #pragma unroll
    for (int off = 32; off > 0; off >>= 1)
        acc += __shfl_down(acc, off, 64);

    __shared__ float sdata[NT / 64];
    const int lane = threadIdx.x & 63;
    const int wid  = threadIdx.x >> 6;
    if (lane == 0) sdata[wid] = acc;
    __syncthreads();
    if (threadIdx.x == 0) {
        float b = 0.0f;
        #pragma unroll
        for (int w = 0; w < NT / 64; ++w) b += sdata[w];
        partial[blockIdx.x] = b;
    }
}

__global__ __launch_bounds__(NT) void reduce_final(
    const float* __restrict__ partial, float* __restrict__ out, int n)
{
    float acc = 0.0f;
    for (int i = threadIdx.x; i < n; i += NT) acc += partial[i];

    #pragma unroll
    for (int off = 32; off > 0; off >>= 1)
        acc += __shfl_down(acc, off, 64);

    __shared__ float sdata[NT / 64];
    const int lane = threadIdx.x & 63;
    const int wid  = threadIdx.x >> 6;
    if (lane == 0) sdata[wid] = acc;
    __syncthreads();
    if (threadIdx.x == 0) {
        float b = 0.0f;
        #pragma unroll
        for (int w = 0; w < NT / 64; ++w) b += sdata[w];
        out[0] = b;
    }
}

extern "C" void kernel_launch(void* const* d_in, const int* in_sizes, int n_in,
                              void* d_out, int out_size, void* d_ws, size_t ws_size,
                              hipStream_t stream) {
    const float* est = (const float*)d_in[0];
    const float* obs = (const float*)d_in[1];
    const float* sn  = (const float*)d_in[2];
    const int n  = in_sizes[0];
    const int n4 = n / 4;
    float* partial = (float*)d_ws;  // NB floats = 8 KB scratch

    rician_partial<<<NB, NT, 0, stream>>>(
        (const float4*)est, (const float4*)obs, est, obs, sn, partial, n4, n);
    reduce_final<<<1, NT, 0, stream>>>(partial, (float*)d_out, NB);
}